// Round 14
// baseline (595.146 us; speedup 1.0000x reference)
//
#include <hip/hip_runtime.h>
#include <hip/hip_cooperative_groups.h>

namespace cg = cooperative_groups;

#define N_NODES 100000
#define N_EDGES 1600000
#define BSHIFT 9
#define BNODES 512                                  // nodes per bucket (2^BSHIFT)
#define NB ((N_NODES + BNODES - 1) / BNODES)        // 196 buckets
#define CAP 10240                                   // padded bucket capacity (mean 8192, +22 sigma)
#define TILE 2048
#define EPT 8                                       // edges/thread in redistribute (256 thr)

typedef _Float16 half8 __attribute__((ext_vector_type(8)));
typedef _Float16 half4 __attribute__((ext_vector_type(4)));
typedef float floatx4 __attribute__((ext_vector_type(4)));

union SharedU {
    struct {  // redistribute phase (19.5 KB max member)
        int cnt[256], gdelta[256], lcur[256], wsum[4];
        int sorted[TILE], sdelta[TILE];
    } r;
    struct {  // bucket_csr phase
        int hist[BNODES], cur[BNODES];
        float dinvS[BNODES];
        int wsum[4];
    } c;
    struct { _Float16 aggS[64][40]; } f1;   // stride 40 fp16 = 80B -> 2-way banks
    struct { _Float16 aggS[32][72]; } f2;   // stride 72 fp16 = 144B -> 2-way banks
};

__device__ void packW_dev(const float* __restrict__ W, _Float16* __restrict__ Wp, int IC) {
    int total = IC * 64;
    for (int idx = threadIdx.x; idx < total; idx += 256) {
        int j = idx & 7;
        int l = (idx >> 3) & 63;
        int cbks = idx >> 9;
        int cb = cbks & 3;
        int ks = cbks >> 2;
        int k = ks * 32 + (l >> 4) * 8 + j;
        int c = cb * 16 + (l & 15);
        Wp[idx] = (_Float16)W[k * 64 + c];
    }
}

__global__ __launch_bounds__(256, 8) void k_mega(
        const int* __restrict__ src, const int* __restrict__ dst,
        const float* __restrict__ X,
        const float* __restrict__ W1, const float* __restrict__ b1,
        const float* __restrict__ W2, const float* __restrict__ b2,
        int* __restrict__ bucketCur, int* __restrict__ packed,
        int* __restrict__ rowbeg, int* __restrict__ rowend,
        int* __restrict__ col, float* __restrict__ dinv,
        _Float16* __restrict__ Wp1, _Float16* __restrict__ Wp2,
        _Float16* __restrict__ xh1, _Float16* __restrict__ xh2,
        float* __restrict__ outF) {
    cg::grid_group grid = cg::this_grid();
    __shared__ SharedU S;
    const int t = threadIdx.x;
    const int nblk = gridDim.x;
    const int lane = t & 63, wid = t >> 6;

    // ---------- phase 0: init bucket cursors + pack W ----------
    if (blockIdx.x == 0) {
        if (t < NB) bucketCur[t] = t * CAP;
    } else if (blockIdx.x == 1) {
        packW_dev(W1, Wp1, 32);
    } else if (blockIdx.x == 2) {
        packW_dev(W2, Wp2, 64);
    }
    grid.sync();

    // ---------- phase 1: redistribute (tile-local bucket sort -> padded regions) ----------
    {
        const int nTiles = (N_EDGES + TILE - 1) / TILE;
        for (int tile = blockIdx.x; tile < nTiles; tile += nblk) {
            int tileBase = tile * TILE;
            int tileCnt = min(TILE, N_EDGES - tileBase);
            S.r.cnt[t] = 0;
            __syncthreads();
            int pk[EPT], bk[EPT];
#pragma unroll
            for (int k = 0; k < EPT; ++k) {
                int i = k * 256 + t;
                if (i < tileCnt) {
                    int d = dst[tileBase + i];
                    int s = src[tileBase + i];
                    bk[k] = d >> BSHIFT;
                    pk[k] = (s << BSHIFT) | (d & (BNODES - 1));
                    atomicAdd(&S.r.cnt[bk[k]], 1);
                } else bk[k] = -1;
            }
            __syncthreads();
            int v = S.r.cnt[t];
            int sc = v;
#pragma unroll
            for (int o = 1; o < 64; o <<= 1) {
                int u = __shfl_up(sc, o, 64);
                if (lane >= o) sc += u;
            }
            if (lane == 63) S.r.wsum[wid] = sc;
            __syncthreads();
            if (t == 0) {
                int run = 0;
#pragma unroll
                for (int w = 0; w < 4; ++w) { int x2 = S.r.wsum[w]; S.r.wsum[w] = run; run += x2; }
            }
            __syncthreads();
            int excl = sc + S.r.wsum[wid] - v;
            S.r.lcur[t] = excl;
            if (t < NB && v > 0)
                S.r.gdelta[t] = atomicAdd(&bucketCur[t], v) - excl;
            __syncthreads();
#pragma unroll
            for (int k = 0; k < EPT; ++k) {
                if (bk[k] >= 0) {
                    int l = atomicAdd(&S.r.lcur[bk[k]], 1);
                    S.r.sorted[l] = pk[k];
                    S.r.sdelta[l] = S.r.gdelta[bk[k]];
                }
            }
            __syncthreads();
            for (int i = t; i < tileCnt; i += 256)
                packed[i + S.r.sdelta[i]] = S.r.sorted[i];
            __syncthreads();
        }
    }
    grid.sync();

    // ---------- phase 2: per-bucket CSR + dinv + fp16 prescale (256 thr, 2 nodes/thr) ----------
    {
        for (int b = blockIdx.x; b < NB; b += nblk) {
            int node0 = b * BNODES;
            int nn = min(BNODES, N_NODES - node0);
            int eb = b * CAP;
            int ee = bucketCur[b];
            S.c.hist[t] = 0;
            S.c.hist[t + 256] = 0;
            __syncthreads();
            for (int i = eb + t; i < ee; i += 256)
                atomicAdd(&S.c.hist[packed[i] & (BNODES - 1)], 1);
            __syncthreads();
            int v0 = S.c.hist[2 * t], v1 = S.c.hist[2 * t + 1];
            int ps = v0 + v1;
            int sc = ps;
#pragma unroll
            for (int o = 1; o < 64; o <<= 1) {
                int u = __shfl_up(sc, o, 64);
                if (lane >= o) sc += u;
            }
            if (lane == 63) S.c.wsum[wid] = sc;
            __syncthreads();
            if (t == 0) {
                int run = 0;
#pragma unroll
                for (int w = 0; w < 4; ++w) { int x2 = S.c.wsum[w]; S.c.wsum[w] = run; run += x2; }
            }
            __syncthreads();
            int excl = sc - ps + S.c.wsum[wid];
            S.c.cur[2 * t] = excl;
            S.c.cur[2 * t + 1] = excl + v0;
            float di0 = rsqrtf((float)(1 + v0));
            float di1 = rsqrtf((float)(1 + v1));
            S.c.dinvS[2 * t] = di0;
            S.c.dinvS[2 * t + 1] = di1;
            if (2 * t < nn) {
                rowbeg[node0 + 2 * t] = eb + excl;
                rowend[node0 + 2 * t] = eb + excl + v0;
                dinv[node0 + 2 * t] = di0;
            }
            if (2 * t + 1 < nn) {
                rowbeg[node0 + 2 * t + 1] = eb + excl + v0;
                rowend[node0 + 2 * t + 1] = eb + excl + v0 + v1;
                dinv[node0 + 2 * t + 1] = di1;
            }
            __syncthreads();
            for (int i = eb + t; i < ee; i += 256) {
                int p = packed[i];
                int dl = p & (BNODES - 1);
                int l = atomicAdd(&S.c.cur[dl], 1);
                col[eb + l] = p >> BSHIFT;
            }
            const float4* X4 = (const float4*)X;
            half4* U4 = (half4*)xh1;
            for (int i = t; i < nn * 8; i += 256) {
                int nl = i >> 3;
                float4 vv = X4[(size_t)(node0 + nl) * 8 + (i & 7)];
                float d2 = S.c.dinvS[nl];
                half4 h;
                h[0] = (_Float16)(vv.x * d2);
                h[1] = (_Float16)(vv.y * d2);
                h[2] = (_Float16)(vv.z * d2);
                h[3] = (_Float16)(vv.w * d2);
                U4[(size_t)(node0 + nl) * 8 + (i & 7)] = h;
            }
            __syncthreads();
        }
    }
    grid.sync();

    // ---------- phase 3: fused1 (gather 32ch + MFMA), 64 nodes/blk-iter ----------
    {
        const int nF1 = (N_NODES + 63) / 64;  // 1563
        for (int blk = blockIdx.x; blk < nF1; blk += nblk) {
            int node0 = blk * 64;
            {   // gather: 4 threads/node, 1 half8 each
                int nl = t >> 2, l = t & 3;
                int node = node0 + nl;
                if (node < N_NODES) {
                    const half8* Gr = (const half8*)xh1;
                    half8 s = Gr[(size_t)node * 4 + l];
                    float acc[8];
#pragma unroll
                    for (int q = 0; q < 8; ++q) acc[q] = (float)s[q];
                    int jb = rowbeg[node], je = rowend[node];
                    int j = jb;
                    for (; j + 7 < je; j += 8) {
                        half8 v[8];
#pragma unroll
                        for (int u = 0; u < 8; ++u) v[u] = Gr[(size_t)col[j + u] * 4 + l];
#pragma unroll
                        for (int u = 0; u < 8; ++u)
#pragma unroll
                            for (int q = 0; q < 8; ++q) acc[q] += (float)v[u][q];
                    }
                    for (; j + 1 < je; j += 2) {
                        half8 v0 = Gr[(size_t)col[j] * 4 + l];
                        half8 v1 = Gr[(size_t)col[j + 1] * 4 + l];
#pragma unroll
                        for (int q = 0; q < 8; ++q) acc[q] += (float)v0[q] + (float)v1[q];
                    }
                    if (j < je) {
                        half8 v0 = Gr[(size_t)col[j] * 4 + l];
#pragma unroll
                        for (int q = 0; q < 8; ++q) acc[q] += (float)v0[q];
                    }
                    float di = dinv[node];
                    half8 r;
#pragma unroll
                    for (int q = 0; q < 8; ++q) r[q] = (_Float16)(acc[q] * di);
                    *(half8*)&S.f1.aggS[nl][l * 8] = r;
                }
            }
            __syncthreads();
            {   // MFMA: wave w -> nodes node0 + w*16 .. +15
                int base = wid * 16;
                int nw0 = node0 + base;
                if (nw0 < N_NODES) {
                    half8 af = *(const half8*)&S.f1.aggS[base + (lane & 15)][(lane >> 4) * 8];
                    floatx4 z = {0.f, 0.f, 0.f, 0.f};
                    floatx4 acc[4] = {z, z, z, z};
#pragma unroll
                    for (int cb = 0; cb < 4; ++cb) {
                        half8 bf = ((const half8*)Wp1)[cb * 64 + lane];
                        acc[cb] = __builtin_amdgcn_mfma_f32_16x16x32_f16(af, bf, acc[cb], 0, 0, 0);
                    }
                    int r0 = nw0 + (lane >> 4) * 4;
                    int ch0 = lane & 15;
                    float di[4];
#pragma unroll
                    for (int r = 0; r < 4; ++r) di[r] = dinv[r0 + r];
#pragma unroll
                    for (int cb = 0; cb < 4; ++cb) {
                        int ch = cb * 16 + ch0;
                        float bb = b1[ch];
#pragma unroll
                        for (int r = 0; r < 4; ++r) {
                            float v = acc[cb][r] + bb;
                            v = v > 0.f ? v : 0.f;
                            xh2[(size_t)(r0 + r) * 64 + ch] = (_Float16)(v * di[r]);
                        }
                    }
                }
            }
            __syncthreads();
        }
    }
    grid.sync();

    // ---------- phase 4: fused2 (gather 64ch + MFMA), 32 nodes/blk-iter ----------
    {
        const int nF2 = N_NODES / 32;  // 3125
        for (int blk = blockIdx.x; blk < nF2; blk += nblk) {
            int node0 = blk * 32;
            {   // gather: 8 threads/node, 1 half8 each
                int nl = t >> 3, l = t & 7;
                int node = node0 + nl;
                const half8* Gr = (const half8*)xh2;
                half8 s = Gr[(size_t)node * 8 + l];
                float acc[8];
#pragma unroll
                for (int q = 0; q < 8; ++q) acc[q] = (float)s[q];
                int jb = rowbeg[node], je = rowend[node];
                int j = jb;
                for (; j + 7 < je; j += 8) {
                    half8 v[8];
#pragma unroll
                    for (int u = 0; u < 8; ++u) v[u] = Gr[(size_t)col[j + u] * 8 + l];
#pragma unroll
                    for (int u = 0; u < 8; ++u)
#pragma unroll
                        for (int q = 0; q < 8; ++q) acc[q] += (float)v[u][q];
                }
                for (; j + 1 < je; j += 2) {
                    half8 v0 = Gr[(size_t)col[j] * 8 + l];
                    half8 v1 = Gr[(size_t)col[j + 1] * 8 + l];
#pragma unroll
                    for (int q = 0; q < 8; ++q) acc[q] += (float)v0[q] + (float)v1[q];
                }
                if (j < je) {
                    half8 v0 = Gr[(size_t)col[j] * 8 + l];
#pragma unroll
                    for (int q = 0; q < 8; ++q) acc[q] += (float)v0[q];
                }
                float di = dinv[node];
                half8 r;
#pragma unroll
                for (int q = 0; q < 8; ++q) r[q] = (_Float16)(acc[q] * di);
                *(half8*)&S.f2.aggS[nl][l * 8] = r;
            }
            __syncthreads();
            if (t < 128) {   // MFMA: waves 0,1 -> 16-node tiles; KS=2
                int base = wid * 16;
                int nw0 = node0 + base;
                half8 af0 = *(const half8*)&S.f2.aggS[base + (lane & 15)][(lane >> 4) * 8];
                half8 af1 = *(const half8*)&S.f2.aggS[base + (lane & 15)][(lane >> 4) * 8 + 32];
                floatx4 z = {0.f, 0.f, 0.f, 0.f};
                floatx4 acc[4] = {z, z, z, z};
#pragma unroll
                for (int cb = 0; cb < 4; ++cb) {
                    half8 bf0 = ((const half8*)Wp2)[(0 * 4 + cb) * 64 + lane];
                    half8 bf1 = ((const half8*)Wp2)[(1 * 4 + cb) * 64 + lane];
                    acc[cb] = __builtin_amdgcn_mfma_f32_16x16x32_f16(af0, bf0, acc[cb], 0, 0, 0);
                    acc[cb] = __builtin_amdgcn_mfma_f32_16x16x32_f16(af1, bf1, acc[cb], 0, 0, 0);
                }
                int r0 = nw0 + (lane >> 4) * 4;
                int ch0 = lane & 15;
#pragma unroll
                for (int cb = 0; cb < 4; ++cb) {
                    int ch = cb * 16 + ch0;
                    float bb = b2[ch];
#pragma unroll
                    for (int r = 0; r < 4; ++r) {
                        float v = acc[cb][r] + bb;
                        outF[(size_t)(r0 + r) * 64 + ch] = v > 0.f ? v : 0.f;
                    }
                }
            }
            __syncthreads();
        }
    }
}

// ---------------- launch ----------------

extern "C" void kernel_launch(void* const* d_in, const int* in_sizes, int n_in,
                              void* d_out, int out_size, void* d_ws, size_t ws_size,
                              hipStream_t stream) {
    const float* x  = (const float*)d_in[0];
    const int* ei   = (const int*)d_in[1];   // [2, E] row-major, int32
    const float* W1 = (const float*)d_in[2];
    const float* b1 = (const float*)d_in[3];
    const float* W2 = (const float*)d_in[4];
    const float* b2 = (const float*)d_in[5];

    const int* src = ei;              // edge_index[0]
    const int* dst = ei + N_EDGES;    // edge_index[1]

    // workspace layout (512B aligned blocks)
    char* ws = (char*)d_ws;
    size_t off = 0;
    auto alloc = [&](size_t bytes) { void* p = ws + off; off = (off + bytes + 511) & ~511ull; return p; };
    int*   bucketCur  = (int*)  alloc((size_t)NB * 4);
    int*   packed     = (int*)  alloc((size_t)NB * CAP * 4);    // 8.0 MB padded
    int*   rowbeg     = (int*)  alloc((size_t)N_NODES * 4);
    int*   rowend     = (int*)  alloc((size_t)N_NODES * 4);
    int*   col        = (int*)  alloc((size_t)NB * CAP * 4);    // 8.0 MB padded
    float* dinv       = (float*)alloc((size_t)N_NODES * 4);
    _Float16* Wp1     = (_Float16*)alloc((size_t)32 * 64 * 2);
    _Float16* Wp2     = (_Float16*)alloc((size_t)64 * 64 * 2);
    _Float16* xh1     = (_Float16*)alloc((size_t)N_NODES * 32 * 2);   // 6.4 MB
    _Float16* xh2     = (_Float16*)alloc((size_t)N_NODES * 64 * 2);   // 12.8 MB
    float* outF       = (float*)d_out;

    // cooperative grid: all blocks co-resident (occupancy-derived, deterministic)
    int dev = 0;
    hipGetDevice(&dev);
    int numCU = 256;
    hipDeviceGetAttribute(&numCU, hipDeviceAttributeMultiprocessorCount, dev);
    int maxBpc = 1;
    hipOccupancyMaxActiveBlocksPerMultiprocessor(&maxBpc, (const void*)k_mega, 256, 0);
    long grid = (long)numCU * maxBpc;
    if (grid > 3125) grid = 3125;   // largest phase extent
    if (grid < 3) grid = 3;         // phase 0 uses blocks 0..2

    void* args[] = {
        (void*)&src, (void*)&dst, (void*)&x,
        (void*)&W1, (void*)&b1, (void*)&W2, (void*)&b2,
        (void*)&bucketCur, (void*)&packed,
        (void*)&rowbeg, (void*)&rowend,
        (void*)&col, (void*)&dinv,
        (void*)&Wp1, (void*)&Wp2,
        (void*)&xh1, (void*)&xh2,
        (void*)&outF,
    };
    hipLaunchCooperativeKernel((const void*)k_mega, dim3((uint32_t)grid), dim3(256),
                               args, 0, stream);
}

// Round 15
// 102.518 us; speedup vs baseline: 5.8053x; 5.8053x over previous
//
#include <hip/hip_runtime.h>

#define N_NODES 100000
#define N_EDGES 1600000
#define BSHIFT 9
#define BNODES 512                                  // nodes per bucket (2^BSHIFT)
#define NB ((N_NODES + BNODES - 1) / BNODES)        // 196 buckets
#define NBP 256                                     // padded for scans
#define CAP 10240                                   // padded bucket capacity (mean 8192, +22 sigma)
#define TILE 4096
#define EPT 16                                      // edges/thread in redistribute (256 thr)

typedef _Float16 half8 __attribute__((ext_vector_type(8)));
typedef _Float16 half4 __attribute__((ext_vector_type(4)));
typedef float floatx4 __attribute__((ext_vector_type(4)));

// ---------------- CSR build (padded-bucket counting sort) ----------------

__device__ void packW_dev(const float* __restrict__ W, _Float16* __restrict__ Wp, int IC) {
    int total = IC * 64;
    for (int idx = threadIdx.x; idx < total; idx += 256) {
        int j = idx & 7;
        int l = (idx >> 3) & 63;
        int cbks = idx >> 9;
        int cb = cbks & 3;
        int ks = cbks >> 2;
        int k = ks * 32 + (l >> 4) * 8 + j;
        int c = cb * 16 + (l & 15);
        Wp[idx] = (_Float16)W[k * 64 + c];
    }
}

// block 0: init bucket cursors to padded bases; blocks 1,2: pack W1/W2
__global__ __launch_bounds__(256) void k_init_pack(
        int* __restrict__ bucketCur,
        const float* __restrict__ W1, _Float16* __restrict__ Wp1,
        const float* __restrict__ W2, _Float16* __restrict__ Wp2) {
    if (blockIdx.x == 1) { packW_dev(W1, Wp1, 32); return; }
    if (blockIdx.x == 2) { packW_dev(W2, Wp2, 64); return; }
    int t = threadIdx.x;
    if (t < NB) bucketCur[t] = t * CAP;
}

// tile-local counting sort by bucket, then coalesced append into padded bucket regions
// int4-vectorized edge loads (TILE and E are multiples of 4)
__global__ __launch_bounds__(256) void k_redistribute(
        const int* __restrict__ src, const int* __restrict__ dst,
        int* __restrict__ bucketCur, int* __restrict__ packed, int e) {
    __shared__ int cnt[NBP], gdelta[NBP], lcur[NBP];
    __shared__ int wsum[4];
    __shared__ int sorted[TILE];
    __shared__ int sdelta[TILE];
    int tileBase = blockIdx.x * TILE;
    int tileCnt = min(TILE, e - tileBase);
    int t = threadIdx.x;
    for (int i = t; i < NBP; i += 256) cnt[i] = 0;
    __syncthreads();
    int pk[EPT], bk[EPT];
#pragma unroll
    for (int k4 = 0; k4 < EPT / 4; ++k4) {
        int base = (k4 * 256 + t) * 4;
        if (base < tileCnt) {  // tileCnt % 4 == 0 -> all 4 valid
            int4 s4 = *(const int4*)(src + tileBase + base);
            int4 d4 = *(const int4*)(dst + tileBase + base);
            int ss[4] = {s4.x, s4.y, s4.z, s4.w};
            int dd[4] = {d4.x, d4.y, d4.z, d4.w};
#pragma unroll
            for (int u = 0; u < 4; ++u) {
                int k = k4 * 4 + u;
                bk[k] = dd[u] >> BSHIFT;
                pk[k] = (ss[u] << BSHIFT) | (dd[u] & (BNODES - 1));
                atomicAdd(&cnt[bk[k]], 1);
            }
        } else {
#pragma unroll
            for (int u = 0; u < 4; ++u) bk[k4 * 4 + u] = -1;
        }
    }
    __syncthreads();
    // wave-shuffle exclusive scan of cnt[0..255] (4 waves)
    {
        int lane = t & 63, wid = t >> 6;
        int v = cnt[t];
        int sc = v;
#pragma unroll
        for (int o = 1; o < 64; o <<= 1) {
            int u = __shfl_up(sc, o, 64);
            if (lane >= o) sc += u;
        }
        if (lane == 63) wsum[wid] = sc;
        __syncthreads();
        if (t == 0) {
            int run = 0;
#pragma unroll
            for (int w = 0; w < 4; ++w) { int x2 = wsum[w]; wsum[w] = run; run += x2; }
        }
        __syncthreads();
        int excl = sc + wsum[wid] - v;
        lcur[t] = excl;
        if (t < NB && v > 0)
            gdelta[t] = atomicAdd(&bucketCur[t], v) - excl;
    }
    __syncthreads();
#pragma unroll
    for (int k = 0; k < EPT; ++k) {
        if (bk[k] >= 0) {
            int l = atomicAdd(&lcur[bk[k]], 1);
            sorted[l] = pk[k];
            sdelta[l] = gdelta[bk[k]];
        }
    }
    __syncthreads();
    for (int i = t; i < tileCnt; i += 256)
        packed[i + sdelta[i]] = sorted[i];
}

// one WG per bucket: per-node histogram -> rowbeg/rowend + dinv, local col scatter,
// FUSED: fp16 prescale of this bucket's x rows. int4-vectorized packed reads.
__global__ __launch_bounds__(512) void k_bucket_csr(
        const int* __restrict__ packed, const int* __restrict__ bucketCur,
        int* __restrict__ rowbeg, int* __restrict__ rowend,
        int* __restrict__ col, float* __restrict__ dinv,
        const float* __restrict__ X, _Float16* __restrict__ xh1, int n) {
    __shared__ int hist[BNODES], cur[BNODES];
    __shared__ int wsum[8];
    __shared__ float dinvS[BNODES];
    int b = blockIdx.x;
    int node0 = b * BNODES;
    int nn = min(BNODES, n - node0);
    int eb = b * CAP;            // 16B-aligned (CAP*4 % 16 == 0)
    int ee = bucketCur[b];
    int nv = ee - eb;
    int nv4 = nv >> 2;
    const int4* p4 = (const int4*)(packed + eb);
    int t = threadIdx.x;  // 512 threads
    hist[t] = 0;
    __syncthreads();
    for (int i = t; i < nv4; i += 512) {
        int4 pp = p4[i];
        atomicAdd(&hist[pp.x & (BNODES - 1)], 1);
        atomicAdd(&hist[pp.y & (BNODES - 1)], 1);
        atomicAdd(&hist[pp.z & (BNODES - 1)], 1);
        atomicAdd(&hist[pp.w & (BNODES - 1)], 1);
    }
    for (int i = eb + (nv4 << 2) + t; i < ee; i += 512)
        atomicAdd(&hist[packed[i] & (BNODES - 1)], 1);
    __syncthreads();
    // wave-shuffle exclusive scan of hist[0..511] (8 waves)
    int lane = t & 63, wid = t >> 6;
    int v = hist[t];
    int sc = v;
#pragma unroll
    for (int o = 1; o < 64; o <<= 1) {
        int u = __shfl_up(sc, o, 64);
        if (lane >= o) sc += u;
    }
    if (lane == 63) wsum[wid] = sc;
    __syncthreads();
    if (t == 0) {
        int run = 0;
#pragma unroll
        for (int w = 0; w < 8; ++w) { int x2 = wsum[w]; wsum[w] = run; run += x2; }
    }
    __syncthreads();
    int excl = sc + wsum[wid] - v;
    cur[t] = excl;
    float di = rsqrtf((float)(1 + v));
    dinvS[t] = di;
    if (t < nn) {
        rowbeg[node0 + t] = eb + excl;
        rowend[node0 + t] = eb + excl + v;
        dinv[node0 + t] = di;
    }
    __syncthreads();
    // col scatter (~40KB L2-local region), 4 edges per int4
    for (int i = t; i < nv4; i += 512) {
        int4 pp = p4[i];
        int e0[4] = {pp.x, pp.y, pp.z, pp.w};
#pragma unroll
        for (int u = 0; u < 4; ++u) {
            int dl = e0[u] & (BNODES - 1);
            int l = atomicAdd(&cur[dl], 1);
            col[eb + l] = e0[u] >> BSHIFT;
        }
    }
    for (int i = eb + (nv4 << 2) + t; i < ee; i += 512) {
        int p = packed[i];
        int dl = p & (BNODES - 1);
        int l = atomicAdd(&cur[dl], 1);
        col[eb + l] = p >> BSHIFT;
    }
    // fused prescale: xh1[node] = fp16(dinv[node] * x[node]), 8 float4 per row
    const float4* X4 = (const float4*)X;
    half4* U4 = (half4*)xh1;
    for (int i = t; i < nn * 8; i += 512) {
        int nl = i >> 3;
        float4 vv = X4[(size_t)(node0 + nl) * 8 + (i & 7)];
        float d2 = dinvS[nl];
        half4 h;
        h[0] = (_Float16)(vv.x * d2);
        h[1] = (_Float16)(vv.y * d2);
        h[2] = (_Float16)(vv.z * d2);
        h[3] = (_Float16)(vv.w * d2);
        U4[(size_t)(node0 + nl) * 8 + (i & 7)] = h;
    }
}

// ---------------- fused gather + MFMA GEMM layers ----------------

// Layer 1: 64 nodes/block, 4 thr/node (1 half8 each), unroll-8 edge loop.
// out = fp16(dinv * relu(agg@W1 + b1))
__global__ __launch_bounds__(256) void k_fused1(
        const _Float16* __restrict__ G, const int* __restrict__ rowbeg,
        const int* __restrict__ rowend,
        const int* __restrict__ col, const float* __restrict__ dinv,
        const _Float16* __restrict__ Wp, const float* __restrict__ bias,
        _Float16* __restrict__ out, int n) {
    __shared__ _Float16 aggS[64][40];   // stride 40 fp16 = 80B -> 2-way banks
    const int t = threadIdx.x;
    const int node0 = blockIdx.x * 64;
    {   // gather: 4 threads/node, 1 half8 each
        int nl = t >> 2, l = t & 3;
        int node = node0 + nl;
        if (node < n) {
            const half8* Gr = (const half8*)G;  // 4 half8 per 32ch row
            half8 s = Gr[(size_t)node * 4 + l];
            float acc[8];
#pragma unroll
            for (int q = 0; q < 8; ++q) acc[q] = (float)s[q];
            int jb = rowbeg[node], je = rowend[node];
            int j = jb;
            for (; j + 7 < je; j += 8) {  // unroll-8: 8 row loads in flight
                half8 v[8];
#pragma unroll
                for (int u = 0; u < 8; ++u) v[u] = Gr[(size_t)col[j + u] * 4 + l];
#pragma unroll
                for (int u = 0; u < 8; ++u)
#pragma unroll
                    for (int q = 0; q < 8; ++q) acc[q] += (float)v[u][q];
            }
            for (; j + 1 < je; j += 2) {
                half8 v0 = Gr[(size_t)col[j] * 4 + l];
                half8 v1 = Gr[(size_t)col[j + 1] * 4 + l];
#pragma unroll
                for (int q = 0; q < 8; ++q) acc[q] += (float)v0[q] + (float)v1[q];
            }
            if (j < je) {
                half8 v0 = Gr[(size_t)col[j] * 4 + l];
#pragma unroll
                for (int q = 0; q < 8; ++q) acc[q] += (float)v0[q];
            }
            float di = dinv[node];
            half8 r;
#pragma unroll
            for (int q = 0; q < 8; ++q) r[q] = (_Float16)(acc[q] * di);
            *(half8*)&aggS[nl][l * 8] = r;
        }
    }
    __syncthreads();
    {   // MFMA: wave w -> nodes node0 + w*16 .. +15  (n % 16 == 0)
        const int lane = t & 63;
        const int w = t >> 6;
        int base = w * 16;
        int nw0 = node0 + base;
        if (nw0 >= n) return;
        half8 af = *(const half8*)&aggS[base + (lane & 15)][(lane >> 4) * 8];
        floatx4 z = {0.f, 0.f, 0.f, 0.f};
        floatx4 acc[4] = {z, z, z, z};
#pragma unroll
        for (int cb = 0; cb < 4; ++cb) {
            half8 bf = ((const half8*)Wp)[cb * 64 + lane];
            acc[cb] = __builtin_amdgcn_mfma_f32_16x16x32_f16(af, bf, acc[cb], 0, 0, 0);
        }
        int r0 = nw0 + (lane >> 4) * 4;
        int ch0 = lane & 15;
        float di[4];
#pragma unroll
        for (int r = 0; r < 4; ++r) di[r] = dinv[r0 + r];
#pragma unroll
        for (int cb = 0; cb < 4; ++cb) {
            int ch = cb * 16 + ch0;
            float bb = bias[ch];
#pragma unroll
            for (int r = 0; r < 4; ++r) {
                float v = acc[cb][r] + bb;
                v = v > 0.f ? v : 0.f;
                out[(size_t)(r0 + r) * 64 + ch] = (_Float16)(v * di[r]);
            }
        }
    }
}

// Layer 2: 32 nodes/block, 8 thr/node (1 half8 each), unroll-8 edge loop.
// out = f32 relu(agg@W2 + b2)
__global__ __launch_bounds__(256) void k_fused2(
        const _Float16* __restrict__ G, const int* __restrict__ rowbeg,
        const int* __restrict__ rowend,
        const int* __restrict__ col, const float* __restrict__ dinv,
        const _Float16* __restrict__ Wp, const float* __restrict__ bias,
        float* __restrict__ out, int n) {
    __shared__ _Float16 aggS[32][72];   // stride 72 fp16 = 144B -> 2-way banks
    const int t = threadIdx.x;
    const int node0 = blockIdx.x * 32;  // N % 32 == 0 (100000 = 3125*32)
    {   // gather: 8 threads/node, 1 half8 each
        int nl = t >> 3, l = t & 7;
        int node = node0 + nl;
        const half8* Gr = (const half8*)G;  // 8 half8 per 64ch row
        half8 s = Gr[(size_t)node * 8 + l];
        float acc[8];
#pragma unroll
        for (int q = 0; q < 8; ++q) acc[q] = (float)s[q];
        int jb = rowbeg[node], je = rowend[node];
        int j = jb;
        for (; j + 7 < je; j += 8) {  // unroll-8: 8 row loads in flight
            half8 v[8];
#pragma unroll
            for (int u = 0; u < 8; ++u) v[u] = Gr[(size_t)col[j + u] * 8 + l];
#pragma unroll
            for (int u = 0; u < 8; ++u)
#pragma unroll
                for (int q = 0; q < 8; ++q) acc[q] += (float)v[u][q];
        }
        for (; j + 1 < je; j += 2) {
            half8 v0 = Gr[(size_t)col[j] * 8 + l];
            half8 v1 = Gr[(size_t)col[j + 1] * 8 + l];
#pragma unroll
            for (int q = 0; q < 8; ++q) acc[q] += (float)v0[q] + (float)v1[q];
        }
        if (j < je) {
            half8 v0 = Gr[(size_t)col[j] * 8 + l];
#pragma unroll
            for (int q = 0; q < 8; ++q) acc[q] += (float)v0[q];
        }
        float di = dinv[node];
        half8 r;
#pragma unroll
        for (int q = 0; q < 8; ++q) r[q] = (_Float16)(acc[q] * di);
        *(half8*)&aggS[nl][l * 8] = r;
    }
    __syncthreads();
    if (t >= 128) return;
    {   // MFMA: waves 0,1 -> 16-node tiles; KS=2
        const int lane = t & 63;
        const int w = t >> 6;
        int base = w * 16;
        int nw0 = node0 + base;
        half8 af0 = *(const half8*)&aggS[base + (lane & 15)][(lane >> 4) * 8];
        half8 af1 = *(const half8*)&aggS[base + (lane & 15)][(lane >> 4) * 8 + 32];
        floatx4 z = {0.f, 0.f, 0.f, 0.f};
        floatx4 acc[4] = {z, z, z, z};
#pragma unroll
        for (int cb = 0; cb < 4; ++cb) {
            half8 bf0 = ((const half8*)Wp)[(0 * 4 + cb) * 64 + lane];
            half8 bf1 = ((const half8*)Wp)[(1 * 4 + cb) * 64 + lane];
            acc[cb] = __builtin_amdgcn_mfma_f32_16x16x32_f16(af0, bf0, acc[cb], 0, 0, 0);
            acc[cb] = __builtin_amdgcn_mfma_f32_16x16x32_f16(af1, bf1, acc[cb], 0, 0, 0);
        }
        int r0 = nw0 + (lane >> 4) * 4;
        int ch0 = lane & 15;
#pragma unroll
        for (int cb = 0; cb < 4; ++cb) {
            int ch = cb * 16 + ch0;
            float bb = bias[ch];
#pragma unroll
            for (int r = 0; r < 4; ++r) {
                float v = acc[cb][r] + bb;
                out[(size_t)(r0 + r) * 64 + ch] = v > 0.f ? v : 0.f;
            }
        }
    }
}

// ---------------- launch ----------------

extern "C" void kernel_launch(void* const* d_in, const int* in_sizes, int n_in,
                              void* d_out, int out_size, void* d_ws, size_t ws_size,
                              hipStream_t stream) {
    const float* x  = (const float*)d_in[0];
    const int* ei   = (const int*)d_in[1];   // [2, E] row-major, int32
    const float* W1 = (const float*)d_in[2];
    const float* b1 = (const float*)d_in[3];
    const float* W2 = (const float*)d_in[4];
    const float* b2 = (const float*)d_in[5];

    const int N = N_NODES;
    const int E = N_EDGES;
    const int* src = ei;       // edge_index[0]
    const int* dst = ei + E;   // edge_index[1]

    // workspace layout (512B aligned blocks)
    char* ws = (char*)d_ws;
    size_t off = 0;
    auto alloc = [&](size_t bytes) { void* p = ws + off; off = (off + bytes + 511) & ~511ull; return p; };
    int*   bucketCur  = (int*)  alloc((size_t)NB * 4);
    int*   packed     = (int*)  alloc((size_t)NB * CAP * 4);    // 8.0 MB padded
    int*   rowbeg     = (int*)  alloc((size_t)N * 4);
    int*   rowend     = (int*)  alloc((size_t)N * 4);
    int*   col        = (int*)  alloc((size_t)NB * CAP * 4);    // 8.0 MB padded
    float* dinv       = (float*)alloc((size_t)N * 4);
    _Float16* Wp1     = (_Float16*)alloc((size_t)32 * 64 * 2);
    _Float16* Wp2     = (_Float16*)alloc((size_t)64 * 64 * 2);
    _Float16* xh1     = (_Float16*)alloc((size_t)N * 32 * 2);   // 6.4 MB
    _Float16* xh2     = (_Float16*)alloc((size_t)N * 64 * 2);   // 12.8 MB
    float* outF       = (float*)d_out;

    const int B = 256;
    const int nTiles = (E + TILE - 1) / TILE;        // 391

    // ---- CSR build (padded buckets) ----
    k_init_pack<<<3, B, 0, stream>>>(bucketCur, W1, Wp1, W2, Wp2);
    k_redistribute<<<nTiles, B, 0, stream>>>(src, dst, bucketCur, packed, E);
    k_bucket_csr<<<NB, BNODES, 0, stream>>>(packed, bucketCur, rowbeg, rowend, col, dinv, x, xh1, N);

    // ---- layer 1 (gather 32ch + MFMA fused): 64 nodes/block ----
    k_fused1<<<(N + 63) / 64, B, 0, stream>>>(xh1, rowbeg, rowend, col, dinv, Wp1, b1, xh2, N);

    // ---- layer 2 (gather 64ch + MFMA fused): 32 nodes/block ----
    k_fused2<<<N / 32, B, 0, stream>>>(xh2, rowbeg, rowend, col, dinv, Wp2, b2, outF, N);
}